// Round 5
// baseline (214.748 us; speedup 1.0000x reference)
//
#include <hip/hip_runtime.h>

#define NBINS 101
#define NB2 (2 * NBINS)   // 202 bins total (pos + neg)
#define BT 128            // block tile (pairs tile is BT x BT)
#define NTHREADS 256
#define NCOPY 16          // LDS histogram replicas, one per lane&15

typedef _Float16 half8 __attribute__((ext_vector_type(8)));
typedef float floatx4 __attribute__((ext_vector_type(4)));

// ---------------------------------------------------------------------------
// R5: NO LDS tile staging. Each wave loads its MFMA fragments directly from
// global (f32 -> f16 in registers). Evidence: R1-R4 all ~140us regardless of
// atomics/GEMM engine; occupancy 13.9% with 78KB LDS => 1 block/CU, and the
// stage->barrier->compute->barrier structure left SIMDs idle on cold-miss
// latency with nothing to overlap. Now LDS = 14KB (hist replicas + classes),
// launch_bounds(256,3) => 3 blocks/CU, waves run load->MFMA->bin with no
// inter-phase barriers. Per-instr coalescing: 16 fully-used 64B lines per
// dwordx4 (lanes = 16 rows x 32B).
// ---------------------------------------------------------------------------
__global__ __launch_bounds__(NTHREADS, 3)
void hist_pairs_kernel(const float* __restrict__ feats,
                       const int* __restrict__ classes,
                       float* __restrict__ partials,  // [nblocks][NB2]
                       int ntiles) {
    __shared__ float lhist[NB2][NCOPY];
    __shared__ __align__(16) int clsA[BT];
    __shared__ __align__(16) int clsB[BT];

    // blockIdx -> (ti, tj), ti <= tj, row-major over the upper triangle
    int b = blockIdx.x;
    int ti = 0, rem = b;
    while (rem >= ntiles - ti) { rem -= ntiles - ti; ++ti; }
    int tj = ti + rem;
    const int i0 = ti * BT, j0 = tj * BT;
    const int tid = threadIdx.x;

    // zero local histograms (3232 floats)
    for (int t = tid; t < NB2 * NCOPY; t += NTHREADS)
        (&lhist[0][0])[t] = 0.0f;
    if (tid < BT) clsA[tid] = classes[i0 + tid];
    else          clsB[tid - BT] = classes[j0 + tid - BT];
    __syncthreads();

    // each wave owns a 64x64 sub-tile: 4x4 grid of 16x16 MFMA tiles, K=128
    const int wave = tid >> 6;
    const int lane = tid & 63;
    const int wm = (wave >> 1) * 64;
    const int wn = (wave & 1) * 64;
    const int lr = lane & 15;
    const int quad = lane >> 4;

    // lane's global base pointers: row (tile + frag-row + lr), col quad*8
    const float* Abase = feats + (size_t)(i0 + wm + lr) * 128 + quad * 8;
    const float* Bbase = feats + (size_t)(j0 + wn + lr) * 128 + quad * 8;

    floatx4 acc[4][4] = {};
    #pragma unroll
    for (int ks = 0; ks < 128; ks += 32) {
        half8 af[4], bf[4];
        #pragma unroll
        for (int mi = 0; mi < 4; ++mi) {
            const float* p = Abase + (size_t)mi * 16 * 128 + ks;
            float4 f0 = *(const float4*)p;
            float4 f1 = *(const float4*)(p + 4);
            half8 h;
            h[0] = (_Float16)f0.x; h[1] = (_Float16)f0.y;
            h[2] = (_Float16)f0.z; h[3] = (_Float16)f0.w;
            h[4] = (_Float16)f1.x; h[5] = (_Float16)f1.y;
            h[6] = (_Float16)f1.z; h[7] = (_Float16)f1.w;
            af[mi] = h;
        }
        #pragma unroll
        for (int ni = 0; ni < 4; ++ni) {
            const float* p = Bbase + (size_t)ni * 16 * 128 + ks;
            float4 f0 = *(const float4*)p;
            float4 f1 = *(const float4*)(p + 4);
            half8 h;
            h[0] = (_Float16)f0.x; h[1] = (_Float16)f0.y;
            h[2] = (_Float16)f0.z; h[3] = (_Float16)f0.w;
            h[4] = (_Float16)f1.x; h[5] = (_Float16)f1.y;
            h[6] = (_Float16)f1.z; h[7] = (_Float16)f1.w;
            bf[ni] = h;
        }
        #pragma unroll
        for (int mi = 0; mi < 4; ++mi)
            #pragma unroll
            for (int ni = 0; ni < 4; ++ni)
                acc[mi][ni] = __builtin_amdgcn_mfma_f32_16x16x32_f16(
                    af[mi], bf[ni], acc[mi][ni], 0, 0, 0);
    }

    // classes for this lane's C fragment rows/cols
    int cA[4][4], cB[4];
    #pragma unroll
    for (int mi = 0; mi < 4; ++mi) {
        int4 c4 = *(const int4*)&clsA[wm + mi * 16 + quad * 4];
        cA[mi][0] = c4.x; cA[mi][1] = c4.y; cA[mi][2] = c4.z; cA[mi][3] = c4.w;
    }
    #pragma unroll
    for (int ni = 0; ni < 4; ++ni) cB[ni] = clsB[wn + ni * 16 + lr];

    // binning: C-layout col = lane&15, row = quad*4 + reg
    const int copy = lane & (NCOPY - 1);
    const bool diag = (ti == tj);
    #pragma unroll
    for (int mi = 0; mi < 4; ++mi) {
        #pragma unroll
        for (int ni = 0; ni < 4; ++ni) {
            #pragma unroll
            for (int r = 0; r < 4; ++r) {
                const int li = wm + mi * 16 + quad * 4 + r;
                const int lj = wn + ni * 16 + lr;
                if (diag && li >= lj) continue;  // strict upper triangle
                float s = acc[mi][ni][r];
                float pos = (s + 1.0f) * 50.0f;  // (s+1)/step, step=0.02
                int idx = (int)floorf(pos);
                idx = idx < 0 ? 0 : (idx > NBINS - 1 ? NBINS - 1 : idx);
                float frac = pos - (float)idx;
                int hoff = (cA[mi][r] == cB[ni]) ? 0 : NBINS;
                unsafeAtomicAdd(&lhist[hoff + idx][copy], 1.0f - frac);
                int up = idx + 1 > NBINS - 1 ? NBINS - 1 : idx + 1;
                unsafeAtomicAdd(&lhist[hoff + up][copy], frac);
            }
        }
    }
    __syncthreads();

    // merge replicas -> plain coalesced store into this block's partials row
    float* prow = &partials[(size_t)b * NB2];
    for (int t = tid; t < NB2; t += NTHREADS) {
        const float4* row = (const float4*)&lhist[t][0];
        float4 s0 = row[0], s1 = row[1], s2 = row[2], s3 = row[3];
        prow[t] = (s0.x + s0.y + s0.z + s0.w) + (s1.x + s1.y + s1.z + s1.w)
                + (s2.x + s2.y + s2.z + s2.w) + (s3.x + s3.y + s3.z + s3.w);
    }
}

// ---------------------------------------------------------------------------
// Sum 528 partial rows (coalesced, 5-way row split), then fp64 finalize:
// normalize, inclusive cumsum of pos, dot with neg.
// ---------------------------------------------------------------------------
__global__ __launch_bounds__(1024)
void reduce_finalize_kernel(const float* __restrict__ partials,
                            float* __restrict__ out, int nrows) {
    __shared__ float acc[5][NB2];
    __shared__ float h[NB2];
    const int t = threadIdx.x;
    const int g = t / NB2;          // group 0..4 (t >= 1010 idle)
    const int bin = t - g * NB2;
    if (g < 5) {
        float s = 0.0f;
        #pragma unroll 4
        for (int r = g; r < nrows; r += 5)
            s += partials[(size_t)r * NB2 + bin];
        acc[g][bin] = s;
    }
    __syncthreads();
    if (t < NB2)
        h[t] = acc[0][t] + acc[1][t] + acc[2][t] + acc[3][t] + acc[4][t];
    __syncthreads();
    if (t == 0) {
        double sp = 0.0, sn = 0.0;
        for (int k = 0; k < NBINS; ++k) { sp += h[k]; sn += h[NBINS + k]; }
        double isp = 1.0 / sp, isn = 1.0 / sn;
        double cdf = 0.0, res = 0.0;
        for (int k = 0; k < NBINS; ++k) {
            cdf += (double)h[k] * isp;                 // inclusive cumsum of pos
            res += (double)h[NBINS + k] * isn * cdf;   // dot with neg
        }
        out[0] = (float)res;
    }
}

extern "C" void kernel_launch(void* const* d_in, const int* in_sizes, int n_in,
                              void* d_out, int out_size, void* d_ws, size_t ws_size,
                              hipStream_t stream) {
    const float* feats   = (const float*)d_in[0];
    const int*   classes = (const int*)d_in[1];
    float* out      = (float*)d_out;
    float* partials = (float*)d_ws;            // [nblocks][202], plain stores

    int N = in_sizes[1];                       // 4096
    int ntiles = (N + BT - 1) / BT;            // 32
    int nblocks = ntiles * (ntiles + 1) / 2;   // 528

    hist_pairs_kernel<<<nblocks, NTHREADS, 0, stream>>>(feats, classes, partials, ntiles);
    reduce_finalize_kernel<<<1, 1024, 0, stream>>>(partials, out, nblocks);
}

// Round 6
// 205.514 us; speedup vs baseline: 1.0449x; 1.0449x over previous
//
#include <hip/hip_runtime.h>

#define NBINS 101
#define NB2 (2 * NBINS)   // 202 bins total (pos + neg)
#define BT 128            // block tile (pairs tile is BT x BT)
#define NTHREADS 256
#define NCOPY 16          // LDS histogram replicas, one per lane&15

typedef _Float16 half8 __attribute__((ext_vector_type(8)));
typedef _Float16 half4v __attribute__((ext_vector_type(4)));
typedef float floatx4 __attribute__((ext_vector_type(4)));

// ---------------------------------------------------------------------------
// R6 theory: R1-R5 all ran 137-158us with identical FETCH ~8.4MB and
// hbm_gbps ~60-66 regardless of kernel structure => the INPUT buffers sit on
// a ~63 GB/s path (PCIe-like / fine-grained), each XCD re-pulls them, and
// every kernel was stalled behind that. Remedy: cross the slow path exactly
// once (convert kernel: f32 feats -> f16 in d_ws, classes -> u8), then the
// hist kernel reads only the workspace copy (normal device memory).
// ---------------------------------------------------------------------------

__global__ __launch_bounds__(NTHREADS)
void convert_kernel(const float* __restrict__ feats,
                    const int* __restrict__ classes,
                    _Float16* __restrict__ wsF,
                    unsigned char* __restrict__ wsC,
                    int ngroups,   // N*D/8 groups of 8 floats
                    int n) {       // N (classes)
    int t = blockIdx.x * NTHREADS + threadIdx.x;
    if (t < ngroups) {
        const float4* p = (const float4*)feats + (size_t)t * 2;
        float4 f0 = p[0];
        float4 f1 = p[1];
        half8 h;
        h[0] = (_Float16)f0.x; h[1] = (_Float16)f0.y;
        h[2] = (_Float16)f0.z; h[3] = (_Float16)f0.w;
        h[4] = (_Float16)f1.x; h[5] = (_Float16)f1.y;
        h[6] = (_Float16)f1.z; h[7] = (_Float16)f1.w;
        *(half8*)(wsF + (size_t)t * 8) = h;
    }
    if (t < n) wsC[t] = (unsigned char)classes[t];
}

// ---------------------------------------------------------------------------
// One block per 128x128 upper-triangular tile; fragments loaded as half8
// straight from the f16 workspace (one dwordx4 per fragment, no conversion),
// native LDS atomics for binning, plain coalesced partials store.
// ---------------------------------------------------------------------------
__global__ __launch_bounds__(NTHREADS, 4)
void hist_pairs_kernel(const _Float16* __restrict__ feats16,
                       const unsigned char* __restrict__ cls8,
                       float* __restrict__ partials,  // [nblocks][NB2]
                       int ntiles) {
    __shared__ float lhist[NB2][NCOPY];
    __shared__ __align__(16) int clsA[BT];
    __shared__ __align__(16) int clsB[BT];

    // blockIdx -> (ti, tj), ti <= tj, row-major over the upper triangle
    int b = blockIdx.x;
    int ti = 0, rem = b;
    while (rem >= ntiles - ti) { rem -= ntiles - ti; ++ti; }
    int tj = ti + rem;
    const int i0 = ti * BT, j0 = tj * BT;
    const int tid = threadIdx.x;

    // zero local histograms (3232 floats)
    for (int t = tid; t < NB2 * NCOPY; t += NTHREADS)
        (&lhist[0][0])[t] = 0.0f;
    if (tid < BT) clsA[tid] = cls8[i0 + tid];
    else          clsB[tid - BT] = cls8[j0 + tid - BT];
    __syncthreads();

    // each wave owns a 64x64 sub-tile: 4x4 grid of 16x16 MFMA tiles, K=128
    const int wave = tid >> 6;
    const int lane = tid & 63;
    const int wm = (wave >> 1) * 64;
    const int wn = (wave & 1) * 64;
    const int lr = lane & 15;
    const int quad = lane >> 4;

    // lane's base pointers in the f16 workspace
    const _Float16* Abase = feats16 + (size_t)(i0 + wm + lr) * 128 + quad * 8;
    const _Float16* Bbase = feats16 + (size_t)(j0 + wn + lr) * 128 + quad * 8;

    floatx4 acc[4][4] = {};
    #pragma unroll
    for (int ks = 0; ks < 128; ks += 32) {
        half8 af[4], bf[4];
        #pragma unroll
        for (int mi = 0; mi < 4; ++mi)
            af[mi] = *(const half8*)(Abase + (size_t)mi * 16 * 128 + ks);
        #pragma unroll
        for (int ni = 0; ni < 4; ++ni)
            bf[ni] = *(const half8*)(Bbase + (size_t)ni * 16 * 128 + ks);
        #pragma unroll
        for (int mi = 0; mi < 4; ++mi)
            #pragma unroll
            for (int ni = 0; ni < 4; ++ni)
                acc[mi][ni] = __builtin_amdgcn_mfma_f32_16x16x32_f16(
                    af[mi], bf[ni], acc[mi][ni], 0, 0, 0);
    }

    // classes for this lane's C fragment rows/cols
    int cA[4][4], cB[4];
    #pragma unroll
    for (int mi = 0; mi < 4; ++mi) {
        int4 c4 = *(const int4*)&clsA[wm + mi * 16 + quad * 4];
        cA[mi][0] = c4.x; cA[mi][1] = c4.y; cA[mi][2] = c4.z; cA[mi][3] = c4.w;
    }
    #pragma unroll
    for (int ni = 0; ni < 4; ++ni) cB[ni] = clsB[wn + ni * 16 + lr];

    // binning: C-layout col = lane&15, row = quad*4 + reg
    const int copy = lane & (NCOPY - 1);
    const bool diag = (ti == tj);
    #pragma unroll
    for (int mi = 0; mi < 4; ++mi) {
        #pragma unroll
        for (int ni = 0; ni < 4; ++ni) {
            #pragma unroll
            for (int r = 0; r < 4; ++r) {
                const int li = wm + mi * 16 + quad * 4 + r;
                const int lj = wn + ni * 16 + lr;
                if (diag && li >= lj) continue;  // strict upper triangle
                float s = acc[mi][ni][r];
                float pos = (s + 1.0f) * 50.0f;  // (s+1)/step, step=0.02
                int idx = (int)floorf(pos);
                idx = idx < 0 ? 0 : (idx > NBINS - 1 ? NBINS - 1 : idx);
                float frac = pos - (float)idx;
                int hoff = (cA[mi][r] == cB[ni]) ? 0 : NBINS;
                unsafeAtomicAdd(&lhist[hoff + idx][copy], 1.0f - frac);
                int up = idx + 1 > NBINS - 1 ? NBINS - 1 : idx + 1;
                unsafeAtomicAdd(&lhist[hoff + up][copy], frac);
            }
        }
    }
    __syncthreads();

    // merge replicas -> plain coalesced store into this block's partials row
    float* prow = &partials[(size_t)b * NB2];
    for (int t = tid; t < NB2; t += NTHREADS) {
        const float4* row = (const float4*)&lhist[t][0];
        float4 s0 = row[0], s1 = row[1], s2 = row[2], s3 = row[3];
        prow[t] = (s0.x + s0.y + s0.z + s0.w) + (s1.x + s1.y + s1.z + s1.w)
                + (s2.x + s2.y + s2.z + s2.w) + (s3.x + s3.y + s3.z + s3.w);
    }
}

// ---------------------------------------------------------------------------
// Sum 528 partial rows (coalesced, 5-way row split), then fp64 finalize:
// normalize, inclusive cumsum of pos, dot with neg.
// ---------------------------------------------------------------------------
__global__ __launch_bounds__(1024)
void reduce_finalize_kernel(const float* __restrict__ partials,
                            float* __restrict__ out, int nrows) {
    __shared__ float acc[5][NB2];
    __shared__ float h[NB2];
    const int t = threadIdx.x;
    const int g = t / NB2;          // group 0..4 (t >= 1010 idle)
    const int bin = t - g * NB2;
    if (g < 5) {
        float s = 0.0f;
        #pragma unroll 4
        for (int r = g; r < nrows; r += 5)
            s += partials[(size_t)r * NB2 + bin];
        acc[g][bin] = s;
    }
    __syncthreads();
    if (t < NB2)
        h[t] = acc[0][t] + acc[1][t] + acc[2][t] + acc[3][t] + acc[4][t];
    __syncthreads();
    if (t == 0) {
        double sp = 0.0, sn = 0.0;
        for (int k = 0; k < NBINS; ++k) { sp += h[k]; sn += h[NBINS + k]; }
        double isp = 1.0 / sp, isn = 1.0 / sn;
        double cdf = 0.0, res = 0.0;
        for (int k = 0; k < NBINS; ++k) {
            cdf += (double)h[k] * isp;                 // inclusive cumsum of pos
            res += (double)h[NBINS + k] * isn * cdf;   // dot with neg
        }
        out[0] = (float)res;
    }
}

extern "C" void kernel_launch(void* const* d_in, const int* in_sizes, int n_in,
                              void* d_out, int out_size, void* d_ws, size_t ws_size,
                              hipStream_t stream) {
    const float* feats   = (const float*)d_in[0];
    const int*   classes = (const int*)d_in[1];
    float* out = (float*)d_out;

    int N = in_sizes[1];                       // 4096
    int D = in_sizes[0] / N;                   // 128
    int ntiles = (N + BT - 1) / BT;            // 32
    int nblocks = ntiles * (ntiles + 1) / 2;   // 528

    // workspace layout: f16 feats | u8 classes | fp32 partials
    _Float16* wsF = (_Float16*)d_ws;
    unsigned char* wsC = (unsigned char*)(wsF + (size_t)N * D);
    float* partials = (float*)(wsC + ((N + 15) & ~15));

    int ngroups = N * D / 8;                   // 65536 groups of 8 floats
    int cblocks = (ngroups + NTHREADS - 1) / NTHREADS;
    convert_kernel<<<cblocks, NTHREADS, 0, stream>>>(feats, classes, wsF, wsC,
                                                     ngroups, N);
    hist_pairs_kernel<<<nblocks, NTHREADS, 0, stream>>>(wsF, wsC, partials, ntiles);
    reduce_finalize_kernel<<<1, 1024, 0, stream>>>(partials, out, nblocks);
}

// Round 7
// 89.085 us; speedup vs baseline: 2.4106x; 2.3069x over previous
//
#include <hip/hip_runtime.h>

#define NBINS 101
#define NB2 (2 * NBINS)   // 202 bins total (pos + neg)
#define BT 128            // block tile (pairs tile is BT x BT)
#define NTHREADS 256
#define NCOPY 32          // histogram replicas, one per lane&31 (bank = copy)

#define FRAC_BITS 12
#define FRAC_SCALE 4096.0f
#define CNT_SHIFT 22
#define FRAC_MASK ((1u << CNT_SHIFT) - 1)

typedef _Float16 half8 __attribute__((ext_vector_type(8)));
typedef float floatx4 __attribute__((ext_vector_type(4)));

// ---------------------------------------------------------------------------
// R7 theory: across R1-R6 every structural change (GEMM engine, staging,
// global traffic, global atomics) left dur at ~140us. The only invariant
// workload is the ~16.8M data-dependent LDS atomic lane-ops of the binning.
// => hypothesis: LDS atomic unit retires scattered atomic lane-ops at
// ~0.25-0.5/cyc/CU -> 110-130us floor. Fix: ONE packed u32 atomic per pair
// instead of two f32 atomics: word = (1<<22) | round(frac*4096) added to bin
// idx; then hist[k] = C[k]-F[k]+F[k-1] (telescoped per block, edge-folded to
// match the reference clamp). Overflow-proof: <=512 ops per (bin,copy) per
// block => sumF <= 2^21 < 2^22, count <= 512 < 2^10. copy = lane&31 => bank
// conflict-free, <=2-way same-address.
// ---------------------------------------------------------------------------

__global__ __launch_bounds__(NTHREADS)
void convert_kernel(const float* __restrict__ feats,
                    const int* __restrict__ classes,
                    _Float16* __restrict__ wsF,
                    unsigned char* __restrict__ wsC,
                    int ngroups,   // N*D/8 groups of 8 floats
                    int n) {       // N (classes)
    int t = blockIdx.x * NTHREADS + threadIdx.x;
    if (t < ngroups) {
        const float4* p = (const float4*)feats + (size_t)t * 2;
        float4 f0 = p[0];
        float4 f1 = p[1];
        half8 h;
        h[0] = (_Float16)f0.x; h[1] = (_Float16)f0.y;
        h[2] = (_Float16)f0.z; h[3] = (_Float16)f0.w;
        h[4] = (_Float16)f1.x; h[5] = (_Float16)f1.y;
        h[6] = (_Float16)f1.z; h[7] = (_Float16)f1.w;
        *(half8*)(wsF + (size_t)t * 8) = h;
    }
    if (t < n) wsC[t] = (unsigned char)classes[t];
}

// ---------------------------------------------------------------------------
// One block per 128x128 upper-triangular tile; half8 fragment loads from the
// f16 workspace; ONE ds_add_u32 per pair; per-block unpack + telescope to a
// 202-float partials row (plain stores).
// ---------------------------------------------------------------------------
__global__ __launch_bounds__(NTHREADS, 4)
void hist_pairs_kernel(const _Float16* __restrict__ feats16,
                       const unsigned char* __restrict__ cls8,
                       float* __restrict__ partials,  // [nblocks][NB2]
                       int ntiles) {
    __shared__ unsigned lhist[NB2][NCOPY];   // packed count|frac, 25.9 KB
    __shared__ float Fbuf[NB2];
    __shared__ __align__(16) int clsA[BT];
    __shared__ __align__(16) int clsB[BT];

    // blockIdx -> (ti, tj), ti <= tj, row-major over the upper triangle
    int b = blockIdx.x;
    int ti = 0, rem = b;
    while (rem >= ntiles - ti) { rem -= ntiles - ti; ++ti; }
    int tj = ti + rem;
    const int i0 = ti * BT, j0 = tj * BT;
    const int tid = threadIdx.x;

    // zero local histograms
    for (int t = tid; t < NB2 * NCOPY; t += NTHREADS)
        (&lhist[0][0])[t] = 0u;
    if (tid < BT) clsA[tid] = cls8[i0 + tid];
    else          clsB[tid - BT] = cls8[j0 + tid - BT];
    __syncthreads();

    // each wave owns a 64x64 sub-tile: 4x4 grid of 16x16 MFMA tiles, K=128
    const int wave = tid >> 6;
    const int lane = tid & 63;
    const int wm = (wave >> 1) * 64;
    const int wn = (wave & 1) * 64;
    const int lr = lane & 15;
    const int quad = lane >> 4;

    const _Float16* Abase = feats16 + (size_t)(i0 + wm + lr) * 128 + quad * 8;
    const _Float16* Bbase = feats16 + (size_t)(j0 + wn + lr) * 128 + quad * 8;

    floatx4 acc[4][4] = {};
    #pragma unroll
    for (int ks = 0; ks < 128; ks += 32) {
        half8 af[4], bf[4];
        #pragma unroll
        for (int mi = 0; mi < 4; ++mi)
            af[mi] = *(const half8*)(Abase + (size_t)mi * 16 * 128 + ks);
        #pragma unroll
        for (int ni = 0; ni < 4; ++ni)
            bf[ni] = *(const half8*)(Bbase + (size_t)ni * 16 * 128 + ks);
        #pragma unroll
        for (int mi = 0; mi < 4; ++mi)
            #pragma unroll
            for (int ni = 0; ni < 4; ++ni)
                acc[mi][ni] = __builtin_amdgcn_mfma_f32_16x16x32_f16(
                    af[mi], bf[ni], acc[mi][ni], 0, 0, 0);
    }

    // classes for this lane's C fragment rows/cols
    int cA[4][4], cB[4];
    #pragma unroll
    for (int mi = 0; mi < 4; ++mi) {
        int4 c4 = *(const int4*)&clsA[wm + mi * 16 + quad * 4];
        cA[mi][0] = c4.x; cA[mi][1] = c4.y; cA[mi][2] = c4.z; cA[mi][3] = c4.w;
    }
    #pragma unroll
    for (int ni = 0; ni < 4; ++ni) cB[ni] = clsB[wn + ni * 16 + lr];

    // binning: ONE packed u32 atomic per pair. C-layout col=lane&15,
    // row = quad*4 + reg.
    const int copy = lane & (NCOPY - 1);
    const bool diag = (ti == tj);
    #pragma unroll
    for (int mi = 0; mi < 4; ++mi) {
        #pragma unroll
        for (int ni = 0; ni < 4; ++ni) {
            #pragma unroll
            for (int r = 0; r < 4; ++r) {
                const int li = wm + mi * 16 + quad * 4 + r;
                const int lj = wn + ni * 16 + lr;
                if (diag && li >= lj) continue;  // strict upper triangle
                float s = acc[mi][ni][r];
                float pos = (s + 1.0f) * 50.0f;  // (s+1)/step, step=0.02
                int idx = (int)floorf(pos);
                idx = idx < 0 ? 0 : (idx > NBINS - 1 ? NBINS - 1 : idx);
                float frac = pos - (float)idx;   // ref: frac after clip
                frac = fminf(fmaxf(frac, 0.0f), 1.0f);
                unsigned word = (1u << CNT_SHIFT)
                              | (unsigned)(frac * FRAC_SCALE + 0.5f);
                int hoff = (cA[mi][r] == cB[ni]) ? 0 : NBINS;
                atomicAdd(&lhist[hoff + idx][copy], word);
            }
        }
    }
    __syncthreads();

    // per-bin unpack: C = sum(w>>22), F = sum(w&mask)/4096
    float myC = 0.0f, myF = 0.0f;
    const int t = tid;               // NTHREADS=256 >= NB2, one bin per thread
    if (t < NB2) {
        unsigned Cs = 0, Fq = 0;
        #pragma unroll
        for (int c = 0; c < NCOPY; ++c) {
            unsigned w = lhist[t][(c + t) & (NCOPY - 1)];
            Cs += w >> CNT_SHIFT;
            Fq += w & FRAC_MASK;     // <= 32 * 2^21 = 2^26, no overflow
        }
        myC = (float)Cs;
        myF = (float)Fq * (1.0f / FRAC_SCALE);
        Fbuf[t] = myF;
    }
    __syncthreads();

    // telescope within each histogram segment:
    // h[t] = C[t] - (t<hi ? F[t] : 0) + (t>lo ? F[t-1] : 0)
    if (t < NB2) {
        const int lo = (t < NBINS) ? 0 : NBINS;
        const int hi = lo + NBINS - 1;
        float h = myC;
        if (t < hi) h -= myF;
        if (t > lo) h += Fbuf[t - 1];
        partials[(size_t)b * NB2 + t] = h;
    }
}

// ---------------------------------------------------------------------------
// Sum 528 partial rows (coalesced, 5-way row split), then fp64 finalize:
// normalize, inclusive cumsum of pos, dot with neg.
// ---------------------------------------------------------------------------
__global__ __launch_bounds__(1024)
void reduce_finalize_kernel(const float* __restrict__ partials,
                            float* __restrict__ out, int nrows) {
    __shared__ float acc[5][NB2];
    __shared__ float h[NB2];
    const int t = threadIdx.x;
    const int g = t / NB2;          // group 0..4 (t >= 1010 idle)
    const int bin = t - g * NB2;
    if (g < 5) {
        float s = 0.0f;
        #pragma unroll 4
        for (int r = g; r < nrows; r += 5)
            s += partials[(size_t)r * NB2 + bin];
        acc[g][bin] = s;
    }
    __syncthreads();
    if (t < NB2)
        h[t] = acc[0][t] + acc[1][t] + acc[2][t] + acc[3][t] + acc[4][t];
    __syncthreads();
    if (t == 0) {
        double sp = 0.0, sn = 0.0;
        for (int k = 0; k < NBINS; ++k) { sp += h[k]; sn += h[NBINS + k]; }
        double isp = 1.0 / sp, isn = 1.0 / sn;
        double cdf = 0.0, res = 0.0;
        for (int k = 0; k < NBINS; ++k) {
            cdf += (double)h[k] * isp;                 // inclusive cumsum of pos
            res += (double)h[NBINS + k] * isn * cdf;   // dot with neg
        }
        out[0] = (float)res;
    }
}

extern "C" void kernel_launch(void* const* d_in, const int* in_sizes, int n_in,
                              void* d_out, int out_size, void* d_ws, size_t ws_size,
                              hipStream_t stream) {
    const float* feats   = (const float*)d_in[0];
    const int*   classes = (const int*)d_in[1];
    float* out = (float*)d_out;

    int N = in_sizes[1];                       // 4096
    int D = in_sizes[0] / N;                   // 128
    int ntiles = (N + BT - 1) / BT;            // 32
    int nblocks = ntiles * (ntiles + 1) / 2;   // 528

    // workspace layout: f16 feats | u8 classes | fp32 partials
    _Float16* wsF = (_Float16*)d_ws;
    unsigned char* wsC = (unsigned char*)(wsF + (size_t)N * D);
    float* partials = (float*)(wsC + ((N + 15) & ~15));

    int ngroups = N * D / 8;                   // 65536 groups of 8 floats
    int cblocks = (ngroups + NTHREADS - 1) / NTHREADS;
    convert_kernel<<<cblocks, NTHREADS, 0, stream>>>(feats, classes, wsF, wsC,
                                                     ngroups, N);
    hist_pairs_kernel<<<nblocks, NTHREADS, 0, stream>>>(wsF, wsC, partials, ntiles);
    reduce_finalize_kernel<<<1, 1024, 0, stream>>>(partials, out, nblocks);
}